// Round 12
// baseline (3773.112 us; speedup 1.0000x reference)
//
#include <hip/hip_runtime.h>
#include <math.h>

// Problem dims
#define B_ 4096
#define HOR_ 32
#define L_ 512
#define A_ 64
#define HID_ 1024

// phase-2 chunking
#define CB 512            // batch rows per chunk
#define MC (CB * HOR_)    // 16384 rows per chunk

typedef unsigned short ushort_t;
typedef __attribute__((ext_vector_type(4))) float f32x4;
typedef __attribute__((ext_vector_type(8))) short s16x8;
typedef __attribute__((ext_vector_type(4))) short s16x4;
typedef __attribute__((ext_vector_type(8))) _Float16 f16x8;

__device__ __forceinline__ unsigned short bf16_rne(float x) {
    unsigned u = __builtin_bit_cast(unsigned, x);
    u += 0x7fffu + ((u >> 16) & 1u);
    return (unsigned short)(u >> 16);
}
__device__ __forceinline__ float bf16_to_f32(unsigned short h) {
    unsigned u = ((unsigned)h) << 16;
    return __builtin_bit_cast(float, u);
}

// XCD-chunked bijective swizzle (requires nwg % 8 == 0; all our grids are).
__device__ __forceinline__ int xcd_swz(int bid, int nwg) {
    return (bid & 7) * (nwg >> 3) + (bid >> 3);
}

// async global->LDS, 16 B per lane; LDS dst = wave-uniform base + lane*16.
__device__ __forceinline__ void gld16(const void* g, void* l) {
    __builtin_amdgcn_global_load_lds(
        (const __attribute__((address_space(1))) void*)g,
        (__attribute__((address_space(3))) void*)l, 16, 0, 0);
}

// ---------------------------------------------------------------------------
// Phase 1: split-fp16 MFMA transition GEMMs.
//   C = act(A @ W^T + bias [+ resid]);  A = Ahi+Alo fp16 pair ([M][K]),
//   W = Whi+Wlo fp16 pair ([N][K]).  3-pass: Ah*Bh + Ah*Bl + Al*Bh, f32 accum.
// Tile BMT x NB, 512 threads, 8 waves as 4(M) x 2(N), wave tile
// (BMT/4) x (NB/2). gload_lds staging into linear [rows][32] LDS,
// double-buffered, 1 barrier/K-step, T1 swizzle.
// Round 12: G1/G2 use 128x128 (96 FLOP/B staged, -33% L2 traffic/FLOP,
// grid 256 = 1 blk/CU); G3 stays 64x64 (grid 512 = 2 blk/CU).
// ---------------------------------------------------------------------------
template <int BMT, int NB, bool TWOSRC, bool SPLIT_OUT, bool RELU, bool RESID,
          bool F32OUT>
__global__ __launch_bounds__(512, (NB == 128 ? 2 : 4)) void trans_gemm(
    const _Float16* __restrict__ Ahi, const _Float16* __restrict__ Alo,
    int lda, int K,
    const float* __restrict__ Aae, int lda_ae, int aoff,
    const _Float16* __restrict__ Whi, const _Float16* __restrict__ Wlo,
    const float* __restrict__ bias,
    const float* __restrict__ resid, int ldr,
    _Float16* __restrict__ Ohi, _Float16* __restrict__ Olo, int ldoh,
    float* __restrict__ Of, int ldof)
{
    constexpr int AF = BMT / 64;                 // M-frags per wave
    constexpr int BF = NB / 32;                  // N-frags per wave

    __shared__ _Float16 Ah[2][BMT][32];
    __shared__ _Float16 Al[2][BMT][32];
    __shared__ _Float16 Bh[2][NB][32];
    __shared__ _Float16 Bl[2][NB][32];

    const int gx = gridDim.x;
    const int bid = xcd_swz(blockIdx.y * gx + blockIdx.x, gx * gridDim.y);
    const int m0 = (bid / gx) * BMT;
    const int n0 = (bid % gx) * NB;

    const int tid = threadIdx.x;
    const int w = tid >> 6, l = tid & 63;
    const int wr = w >> 1, wc = w & 1;           // 4(M) x 2(N) waves
    const int kg = l >> 4, lr = l & 15;

    // staging role assignment: A needs BMT*4 threads, B needs NB*4.
    constexpr int ATH = BMT * 4;
    constexpr int BTH = NB * 4;
    const bool doA = (ATH == 512) || (tid < ATH);
    const bool doB = (ATH == 512) ? ((BTH == 512) || (tid < BTH))
                                  : (tid >= 512 - BTH);
    const int srowA = tid >> 2;
    const int srowB = (ATH == 512) ? (tid >> 2) : ((tid - (512 - BTH)) >> 2);
    const int sg = tid & 3;

    f32x4 acc[AF][BF] = {};
    float4 e0, e1;

    const _Float16* pAh = Ahi + (size_t)(m0 + srowA) * lda + sg * 8;
    const _Float16* pAl = Alo + (size_t)(m0 + srowA) * lda + sg * 8;
    const _Float16* pBh = Whi + (size_t)(n0 + srowB) * K + sg * 8;
    const _Float16* pBl = Wlo + (size_t)(n0 + srowB) * K + sg * 8;
    const float* pAe = TWOSRC
        ? (Aae + (size_t)(m0 + srowA) * lda_ae + aoff + sg * 8 - L_)
        : nullptr;

    auto stage = [&](int buf, int ks) {
        const int k0 = ks * 32;
        if (doB) {
            gld16(pBh + k0, &Bh[buf][srowB][sg * 8]);
            gld16(pBl + k0, &Bl[buf][srowB][sg * 8]);
        }
        if (doA && (!TWOSRC || k0 < L_)) {
            gld16(pAh + k0, &Ah[buf][srowA][sg * 8]);
            gld16(pAl + k0, &Al[buf][srowA][sg * 8]);
        }
    };

    const int NT = K / 32;
    stage(0, 0);
    __syncthreads();
    int cur = 0;

    for (int ks = 0; ks < NT; ++ks) {
        const bool havepf = (ks + 1 < NT);
        const int k0n = (ks + 1) * 32;
        const bool aeNext = TWOSRC && havepf && (k0n >= L_);

        if (havepf) {
            stage(cur ^ 1, ks + 1);
            if (aeNext && doA) {
                e0 = *reinterpret_cast<const float4*>(pAe + k0n);
                e1 = *reinterpret_cast<const float4*>(pAe + k0n + 4);
            }
        }

        f16x8 ah[AF], al[AF], bh[BF], bl[BF];
#pragma unroll
        for (int i = 0; i < AF; ++i) {
            int r = wr * (BMT / 4) + i * 16 + lr;
            ah[i] = *reinterpret_cast<const f16x8*>(&Ah[cur][r][kg * 8]);
            al[i] = *reinterpret_cast<const f16x8*>(&Al[cur][r][kg * 8]);
        }
#pragma unroll
        for (int j = 0; j < BF; ++j) {
            int r = wc * (NB / 2) + j * 16 + lr;
            bh[j] = *reinterpret_cast<const f16x8*>(&Bh[cur][r][kg * 8]);
            bl[j] = *reinterpret_cast<const f16x8*>(&Bl[cur][r][kg * 8]);
        }
#pragma unroll
        for (int i = 0; i < AF; ++i)
#pragma unroll
            for (int j = 0; j < BF; ++j) {
                acc[i][j] = __builtin_amdgcn_mfma_f32_16x16x32_f16(
                    ah[i], bh[j], acc[i][j], 0, 0, 0);
                acc[i][j] = __builtin_amdgcn_mfma_f32_16x16x32_f16(
                    ah[i], bl[j], acc[i][j], 0, 0, 0);
                acc[i][j] = __builtin_amdgcn_mfma_f32_16x16x32_f16(
                    al[i], bh[j], acc[i][j], 0, 0, 0);
            }

        if (havepf) {
            if (aeNext && doA) {
                float vv[8] = {e0.x, e0.y, e0.z, e0.w, e1.x, e1.y, e1.z, e1.w};
                f16x8 h, lo;
#pragma unroll
                for (int j = 0; j < 8; ++j) {
                    _Float16 hh = (_Float16)vv[j];
                    h[j] = hh;
                    lo[j] = (_Float16)(vv[j] - (float)hh);
                }
                *reinterpret_cast<f16x8*>(&Ah[cur ^ 1][srowA][sg * 8]) = h;
                *reinterpret_cast<f16x8*>(&Al[cur ^ 1][srowA][sg * 8]) = lo;
            }
            __syncthreads();
            cur ^= 1;
        }
    }

    float bv[BF];
#pragma unroll
    for (int j = 0; j < BF; ++j)
        bv[j] = bias[n0 + wc * (NB / 2) + j * 16 + lr];

#pragma unroll
    for (int i = 0; i < AF; ++i)
#pragma unroll
        for (int j = 0; j < BF; ++j)
#pragma unroll
            for (int r = 0; r < 4; ++r) {
                int row = m0 + wr * (BMT / 4) + i * 16 + kg * 4 + r;
                int col = n0 + wc * (NB / 2) + j * 16 + lr;
                float v = acc[i][j][r] + bv[j];
                if (RESID)
                    v += resid[(size_t)row * ldr + col];
                if (RELU) v = fmaxf(v, 0.f);
                if (F32OUT)
                    Of[(size_t)row * ldof + col] = v;
                if (SPLIT_OUT) {
                    _Float16 h = (_Float16)v;
                    Ohi[(size_t)row * ldoh + col] = h;
                    Olo[(size_t)row * ldoh + col] = (_Float16)(v - (float)h);
                }
            }
}

// W [K][N] f32 -> Whi/Wlo [N][K] fp16 split (once per call)
__global__ __launch_bounds__(256) void split_transpose(
    const float* __restrict__ W, _Float16* __restrict__ Whi,
    _Float16* __restrict__ Wlo, int K, int N)
{
    int k = blockIdx.x * 256 + threadIdx.x;
    int n = blockIdx.y;
    if (k < K) {
        float v = W[(size_t)k * N + n];
        _Float16 h = (_Float16)v;
        Whi[(size_t)n * K + k] = h;
        Wlo[(size_t)n * K + k] = (_Float16)(v - (float)h);
    }
}

// ae[b,t,:] = action[b,t] @ Wae + bae  for ALL (b,t); one wave per row.
__global__ __launch_bounds__(256) void ae_all(
    const float* __restrict__ actions, const float* __restrict__ Wae,
    const float* __restrict__ bae, float* __restrict__ ae)
{
    const long r = (long)blockIdx.x * 4 + (threadIdx.x >> 6);
    const int c = threadIdx.x & 63;
    const float* arow = actions + r * 64;
    float acc = bae[c];
#pragma unroll 16
    for (int k = 0; k < 64; ++k) acc = fmaf(arow[k], Wae[k * 64 + c], acc);
    ae[r * 64 + c] = acc;
}

// fallback: ae for one step t -> aeS [B][64]
__global__ __launch_bounds__(256) void ae_step(
    const float* __restrict__ actions, const float* __restrict__ Wae,
    const float* __restrict__ bae, int t, float* __restrict__ aeS)
{
    const long b = (long)blockIdx.x * 4 + (threadIdx.x >> 6);
    const int c = threadIdx.x & 63;
    const float* arow = actions + (b * HOR_ + t) * 64;
    float acc = bae[c];
#pragma unroll 16
    for (int k = 0; k < 64; ++k) acc = fmaf(arow[k], Wae[k * 64 + c], acc);
    aeS[b * 64 + c] = acc;
}

// states[:,0,:] = initial; sth/stl = split(initial)
__global__ __launch_bounds__(256) void init_split(
    const float* __restrict__ init, float* __restrict__ states,
    _Float16* __restrict__ sth, _Float16* __restrict__ stl)
{
    size_t i = (size_t)blockIdx.x * 256 + threadIdx.x;
    size_t b = i >> 9, l = i & 511;
    float v = init[i];
    states[b * (33 * L_) + l] = v;
    _Float16 h = (_Float16)v;
    sth[i] = h;
    stl[i] = (_Float16)(v - (float)h);
}

// ---------------- Phase 2: batched bf16 MFMA (obs + harm paths) -------------

// WT[n][k] = bf16(W[k][n])
__global__ __launch_bounds__(256) void cast_transpose(
    const float* __restrict__ W, ushort_t* __restrict__ WT, int K, int N)
{
    int k = blockIdx.x * 256 + threadIdx.x;
    int n = blockIdx.y;
    if (k < K) WT[(long)n * K + k] = bf16_rne(W[(long)k * N + n]);
}

// Per-chunk A-operand split: Ach_hi/lo[m][576] = split_bf16([state_t, act_t])
__global__ __launch_bounds__(256) void split_chunk(
    const float* __restrict__ Sc, const float* __restrict__ Ac,
    ushort_t* __restrict__ Hi, ushort_t* __restrict__ Lo)
{
    size_t i = (size_t)blockIdx.x * 256 + threadIdx.x;   // over MC*144
    int m = (int)(i / 144);
    int g = (int)(i % 144);
    const float* src = (g < 128)
        ? Sc + ((size_t)(m >> 5) * 33 + (m & 31)) * L_ + g * 4
        : Ac + (size_t)m * A_ + (g - 128) * 4;
    float4 v = *reinterpret_cast<const float4*>(src);
    unsigned short h0 = bf16_rne(v.x), h1 = bf16_rne(v.y),
                   h2 = bf16_rne(v.z), h3 = bf16_rne(v.w);
    unsigned short e0 = bf16_rne(v.x - bf16_to_f32(h0));
    unsigned short e1 = bf16_rne(v.y - bf16_to_f32(h1));
    unsigned short e2 = bf16_rne(v.z - bf16_to_f32(h2));
    unsigned short e3 = bf16_rne(v.w - bf16_to_f32(h3));
    s16x4 hv = {(short)h0, (short)h1, (short)h2, (short)h3};
    s16x4 lv = {(short)e0, (short)e1, (short)e2, (short)e3};
    *reinterpret_cast<s16x4*>(&Hi[(size_t)m * 576 + g * 4]) = hv;
    *reinterpret_cast<s16x4*>(&Lo[(size_t)m * 576 + g * 4]) = lv;
}

// Unified phase-2 bf16 GEMM: C = act(A @ WT^T + bias).
template <bool SPLITA, bool RELU, bool BF16OUT>
__global__ __launch_bounds__(512, 4) void mm2(
    const ushort_t* __restrict__ Ahi_g, const ushort_t* __restrict__ Alo_g,
    int lda, int K,
    const ushort_t* __restrict__ WT,
    const float* __restrict__ bias,
    ushort_t* __restrict__ Ob, float* __restrict__ Of, int N)
{
    __shared__ ushort_t Ah[2][128][32];
    __shared__ ushort_t Al[SPLITA ? 2 : 1][128][32];
    __shared__ ushort_t Bt[2][128][32];

    const int gx = gridDim.x;
    const int bid = xcd_swz(blockIdx.y * gx + blockIdx.x, gx * gridDim.y);
    const int m0 = (bid / gx) * 128;
    const int n0 = (bid % gx) * 128;

    const int tid = threadIdx.x;
    const int w = tid >> 6, l = tid & 63;
    const int wr = w >> 1, wc = w & 1;          // 4(M) x 2(N)
    const int kg = l >> 4, lr = l & 15;

    const int srow = tid >> 2, sg = tid & 3;

    f32x4 acc[2][4] = {};

    const ushort_t* pA0 = Ahi_g + (size_t)(m0 + srow) * lda + sg * 8;
    const ushort_t* pA1 = SPLITA
        ? (Alo_g + (size_t)(m0 + srow) * lda + sg * 8) : nullptr;
    const ushort_t* pB = WT + (size_t)(n0 + srow) * K + sg * 8;

    auto stage = [&](int buf, int ks) {
        const int k0 = ks * 32;
        gld16(pB + k0, &Bt[buf][srow][sg * 8]);
        gld16(pA0 + k0, &Ah[buf][srow][sg * 8]);
        if (SPLITA) gld16(pA1 + k0, &Al[SPLITA ? buf : 0][srow][sg * 8]);
    };

    const int NT = K / 32;
    stage(0, 0);
    __syncthreads();
    int cur = 0;

    for (int ks = 0; ks < NT; ++ks) {
        if (ks + 1 < NT) stage(cur ^ 1, ks + 1);

        s16x8 ah[2], al[2], bb[4];
#pragma unroll
        for (int i = 0; i < 2; ++i) {
            int r = wr * 32 + i * 16 + lr;
            ah[i] = *reinterpret_cast<const s16x8*>(&Ah[cur][r][kg * 8]);
            if (SPLITA)
                al[i] = *reinterpret_cast<const s16x8*>(
                    &Al[SPLITA ? cur : 0][r][kg * 8]);
        }
#pragma unroll
        for (int j = 0; j < 4; ++j) {
            int r = wc * 64 + j * 16 + lr;
            bb[j] = *reinterpret_cast<const s16x8*>(&Bt[cur][r][kg * 8]);
        }
#pragma unroll
        for (int i = 0; i < 2; ++i)
#pragma unroll
            for (int j = 0; j < 4; ++j) {
                acc[i][j] = __builtin_amdgcn_mfma_f32_16x16x32_bf16(
                    ah[i], bb[j], acc[i][j], 0, 0, 0);
                if (SPLITA)
                    acc[i][j] = __builtin_amdgcn_mfma_f32_16x16x32_bf16(
                        al[i], bb[j], acc[i][j], 0, 0, 0);
            }

        if (ks + 1 < NT) {
            __syncthreads();
            cur ^= 1;
        }
    }

    float bv[4];
#pragma unroll
    for (int j = 0; j < 4; ++j) bv[j] = bias[n0 + wc * 64 + j * 16 + lr];

#pragma unroll
    for (int i = 0; i < 2; ++i)
#pragma unroll
        for (int j = 0; j < 4; ++j)
#pragma unroll
            for (int r = 0; r < 4; ++r) {
                int row = m0 + wr * 32 + i * 16 + kg * 4 + r;
                int col = n0 + wc * 64 + j * 16 + lr;
                float v = acc[i][j][r] + bv[j];
                if (RELU) v = fmaxf(v, 0.f);
                if (BF16OUT)
                    Ob[(size_t)row * N + col] = bf16_rne(v);
                else
                    Of[(size_t)row * N + col] = v;
            }
}

// ----- fallback phase-2 kernels (reg-staged; used only if ws too small) -----
__global__ __launch_bounds__(256) void mm_split(
    const float* __restrict__ Astate, const float* __restrict__ Aact,
    int Ktot, const ushort_t* __restrict__ WT, int N,
    const float* __restrict__ bias, ushort_t* __restrict__ Out)
{
    __shared__ ushort_t Ahi[128][40];
    __shared__ ushort_t Alo[128][40];
    __shared__ ushort_t Bt[128][40];

    const int tid = threadIdx.x;
    const int m0 = blockIdx.y * 128;
    const int n0 = blockIdx.x * 128;
    const int w = tid >> 6;
    const int l = tid & 63;
    const int wm = w >> 1, wn = w & 1;
    const int kg = l >> 4, lr = l & 15;

    f32x4 acc[4][4] = {};

    for (int k0 = 0; k0 < Ktot; k0 += 32) {
#pragma unroll
        for (int s = 0; s < 4; ++s) {
            int idx = tid + s * 256;
            int arow = idx >> 3;
            int ch = idx & 7;
            int m = m0 + arow;
            const float* src;
            if (k0 < L_) {
                src = Astate + (long)((m >> 5) * 33 + (m & 31)) * L_ + k0 + ch * 4;
            } else {
                src = Aact + (long)m * A_ + (k0 - L_) + ch * 4;
            }
            float4 v = *reinterpret_cast<const float4*>(src);
            unsigned short h0 = bf16_rne(v.x), h1 = bf16_rne(v.y),
                           h2 = bf16_rne(v.z), h3 = bf16_rne(v.w);
            unsigned short e0 = bf16_rne(v.x - bf16_to_f32(h0));
            unsigned short e1 = bf16_rne(v.y - bf16_to_f32(h1));
            unsigned short e2 = bf16_rne(v.z - bf16_to_f32(h2));
            unsigned short e3 = bf16_rne(v.w - bf16_to_f32(h3));
            s16x4 hv = {(short)h0, (short)h1, (short)h2, (short)h3};
            s16x4 lv = {(short)e0, (short)e1, (short)e2, (short)e3};
            *reinterpret_cast<s16x4*>(&Ahi[arow][ch * 4]) = hv;
            *reinterpret_cast<s16x4*>(&Alo[arow][ch * 4]) = lv;
        }
#pragma unroll
        for (int s = 0; s < 2; ++s) {
            int idx = tid + s * 256;
            int brow = idx >> 2;
            int ch = idx & 3;
            s16x8 wv = *reinterpret_cast<const s16x8*>(
                &WT[(long)(n0 + brow) * Ktot + k0 + ch * 8]);
            *reinterpret_cast<s16x8*>(&Bt[brow][ch * 8]) = wv;
        }
        __syncthreads();

        s16x8 ah[4], al[4], bb[4];
#pragma unroll
        for (int i = 0; i < 4; ++i) {
            int r = wm * 64 + i * 16 + lr;
            ah[i] = *reinterpret_cast<const s16x8*>(&Ahi[r][kg * 8]);
            al[i] = *reinterpret_cast<const s16x8*>(&Alo[r][kg * 8]);
        }
#pragma unroll
        for (int j = 0; j < 4; ++j) {
            int r = wn * 64 + j * 16 + lr;
            bb[j] = *reinterpret_cast<const s16x8*>(&Bt[r][kg * 8]);
        }
#pragma unroll
        for (int i = 0; i < 4; ++i)
#pragma unroll
            for (int j = 0; j < 4; ++j) {
                acc[i][j] = __builtin_amdgcn_mfma_f32_16x16x32_bf16(
                    ah[i], bb[j], acc[i][j], 0, 0, 0);
                acc[i][j] = __builtin_amdgcn_mfma_f32_16x16x32_bf16(
                    al[i], bb[j], acc[i][j], 0, 0, 0);
            }
        __syncthreads();
    }

    float bv[4];
#pragma unroll
    for (int j = 0; j < 4; ++j) bv[j] = bias[n0 + wn * 64 + j * 16 + lr];
#pragma unroll
    for (int i = 0; i < 4; ++i)
#pragma unroll
        for (int j = 0; j < 4; ++j)
#pragma unroll
            for (int r = 0; r < 4; ++r) {
                int row = m0 + wm * 64 + i * 16 + kg * 4 + r;
                int col = n0 + wn * 64 + j * 16 + lr;
                float v = fmaxf(acc[i][j][r] + bv[j], 0.f);
                Out[(long)row * N + col] = bf16_rne(v);
            }
}

__global__ __launch_bounds__(256) void mm_bf16(
    const ushort_t* __restrict__ Abf, const ushort_t* __restrict__ WT,
    int N, const float* __restrict__ bias, float* __restrict__ Out)
{
    __shared__ ushort_t At[128][40];
    __shared__ ushort_t Bt[128][40];

    const int tid = threadIdx.x;
    const int m0 = blockIdx.y * 128;
    const int n0 = blockIdx.x * 128;
    const int w = tid >> 6;
    const int l = tid & 63;
    const int wm = w >> 1, wn = w & 1;
    const int kg = l >> 4, lr = l & 15;

    f32x4 acc[4][4] = {};

    for (int k0 = 0; k0 < HID_; k0 += 32) {
#pragma unroll
        for (int s = 0; s < 2; ++s) {
            int idx = tid + s * 256;
            int arow = idx >> 2;
            int ch = idx & 3;
            s16x8 av = *reinterpret_cast<const s16x8*>(
                &Abf[(long)(m0 + arow) * HID_ + k0 + ch * 8]);
            *reinterpret_cast<s16x8*>(&At[arow][ch * 8]) = av;
        }
#pragma unroll
        for (int s = 0; s < 2; ++s) {
            int idx = tid + s * 256;
            int brow = idx >> 2;
            int ch = idx & 3;
            s16x8 wv = *reinterpret_cast<const s16x8*>(
                &WT[(long)(n0 + brow) * HID_ + k0 + ch * 8]);
            *reinterpret_cast<s16x8*>(&Bt[brow][ch * 8]) = wv;
        }
        __syncthreads();

        s16x8 aa[4], bb[4];
#pragma unroll
        for (int i = 0; i < 4; ++i)
            aa[i] = *reinterpret_cast<const s16x8*>(&At[wm * 64 + i * 16 + lr][kg * 8]);
#pragma unroll
        for (int j = 0; j < 4; ++j)
            bb[j] = *reinterpret_cast<const s16x8*>(&Bt[wn * 64 + j * 16 + lr][kg * 8]);
#pragma unroll
        for (int i = 0; i < 4; ++i)
#pragma unroll
            for (int j = 0; j < 4; ++j)
                acc[i][j] = __builtin_amdgcn_mfma_f32_16x16x32_bf16(
                    aa[i], bb[j], acc[i][j], 0, 0, 0);
        __syncthreads();
    }

    float bv[4];
#pragma unroll
    for (int j = 0; j < 4; ++j) bv[j] = bias[n0 + wn * 64 + j * 16 + lr];
#pragma unroll
    for (int i = 0; i < 4; ++i)
#pragma unroll
        for (int j = 0; j < 4; ++j)
#pragma unroll
            for (int r = 0; r < 4; ++r) {
                int row = m0 + wm * 64 + i * 16 + kg * 4 + r;
                int col = n0 + wn * 64 + j * 16 + lr;
                Out[(long)row * N + col] = acc[i][j][r] + bv[j];
            }
}

// harm[m] = sigmoid(hh[m][:] . Wh2 + bh2), one wave per row.
__global__ __launch_bounds__(256) void harm_reduce(
    const ushort_t* __restrict__ hh, const float* __restrict__ Wh2,
    const float* __restrict__ bh2, float* __restrict__ harm)
{
    const int wave = threadIdx.x >> 6;
    const int lane = threadIdx.x & 63;
    const long r = (long)blockIdx.x * 4 + wave;
    const ushort_t* row = hh + r * HID_;
    float s = 0.f;
#pragma unroll
    for (int q = 0; q < 2; ++q) {
        s16x8 a = *reinterpret_cast<const s16x8*>(&row[lane * 16 + q * 8]);
        float4 w0 = *reinterpret_cast<const float4*>(&Wh2[lane * 16 + q * 8]);
        float4 w1 = *reinterpret_cast<const float4*>(&Wh2[lane * 16 + q * 8 + 4]);
        s = fmaf(bf16_to_f32((unsigned short)a[0]), w0.x, s);
        s = fmaf(bf16_to_f32((unsigned short)a[1]), w0.y, s);
        s = fmaf(bf16_to_f32((unsigned short)a[2]), w0.z, s);
        s = fmaf(bf16_to_f32((unsigned short)a[3]), w0.w, s);
        s = fmaf(bf16_to_f32((unsigned short)a[4]), w1.x, s);
        s = fmaf(bf16_to_f32((unsigned short)a[5]), w1.y, s);
        s = fmaf(bf16_to_f32((unsigned short)a[6]), w1.z, s);
        s = fmaf(bf16_to_f32((unsigned short)a[7]), w1.w, s);
    }
#pragma unroll
    for (int off = 32; off; off >>= 1) s += __shfl_down(s, off);
    if (lane == 0) {
        float x = s + bh2[0];
        harm[r] = 1.f / (1.f + expf(-x));
    }
}

// ---------------------------------------------------------------------------
extern "C" void kernel_launch(void* const* d_in, const int* in_sizes, int n_in,
                              void* d_out, int out_size, void* d_ws, size_t ws_size,
                              hipStream_t stream)
{
    const float* initial = (const float*)d_in[0];
    const float* actions = (const float*)d_in[1];
    const float* Wae = (const float*)d_in[2];
    const float* bae = (const float*)d_in[3];
    const float* Wt1 = (const float*)d_in[4];
    const float* bt1 = (const float*)d_in[5];
    const float* Wt2 = (const float*)d_in[6];
    const float* bt2 = (const float*)d_in[7];
    const float* Wt3 = (const float*)d_in[8];
    const float* bt3 = (const float*)d_in[9];
    const float* Wo1 = (const float*)d_in[10];
    const float* bo1 = (const float*)d_in[11];
    const float* Wo2 = (const float*)d_in[12];
    const float* bo2 = (const float*)d_in[13];
    const float* Wh1 = (const float*)d_in[14];
    const float* bh1 = (const float*)d_in[15];
    const float* Wh2 = (const float*)d_in[16];
    const float* bh2 = (const float*)d_in[17];

    float* out = (float*)d_out;
    float* states = out;                                    // [B][33][512]
    float* obs = out + (size_t)B_ * 33 * L_;                // [B][32][512]
    float* harm = obs + (size_t)B_ * HOR_ * L_;             // [B][32]

    // ws layout
    char* wsb = (char*)d_ws;
    size_t off = 0;
    auto alloc = [&](size_t bytes) { char* q = wsb + off; off += bytes; return q; };
    ushort_t* WT_o1 = (ushort_t*)alloc((size_t)HID_ * L_ * 2);
    ushort_t* WT_o2 = (ushort_t*)alloc((size_t)L_ * HID_ * 2);
    ushort_t* WT_h1 = (ushort_t*)alloc((size_t)HID_ * 576 * 2);
    _Float16* Wt1h = (_Float16*)alloc((size_t)HID_ * 576 * 2);
    _Float16* Wt1l = (_Float16*)alloc((size_t)HID_ * 576 * 2);
    _Float16* Wt2h = (_Float16*)alloc((size_t)HID_ * HID_ * 2);
    _Float16* Wt2l = (_Float16*)alloc((size_t)HID_ * HID_ * 2);
    _Float16* Wt3h = (_Float16*)alloc((size_t)L_ * HID_ * 2);
    _Float16* Wt3l = (_Float16*)alloc((size_t)L_ * HID_ * 2);
    _Float16* sth  = (_Float16*)alloc((size_t)B_ * L_ * 2);
    _Float16* stl  = (_Float16*)alloc((size_t)B_ * L_ * 2);
    _Float16* h1h  = (_Float16*)alloc((size_t)B_ * HID_ * 2);
    _Float16* h1l  = (_Float16*)alloc((size_t)B_ * HID_ * 2);
    _Float16* h2h  = (_Float16*)alloc((size_t)B_ * HID_ * 2);
    _Float16* h2l  = (_Float16*)alloc((size_t)B_ * HID_ * 2);
    float* ae = (float*)alloc(0);  // placed last; size depends on mode
    const size_t need_batched = off + (size_t)B_ * HOR_ * A_ * 4;
    const bool batched_ae = (ws_size >= need_batched);

    // phase-2 buffers overlay phase-1 regions (dead after phase 1)
    ushort_t* Ach_hi = (ushort_t*)sth;
    ushort_t* Ach_lo = Ach_hi + (size_t)MC * 576;
    ushort_t* oh2 = (ushort_t*)ae;
    ushort_t* oh_fb = (ushort_t*)h1h;

    // one-time weight prep
    cast_transpose<<<dim3(2, HID_), 256, 0, stream>>>(Wo1, WT_o1, L_, HID_);
    cast_transpose<<<dim3(4, L_), 256, 0, stream>>>(Wo2, WT_o2, HID_, L_);
    cast_transpose<<<dim3(3, HID_), 256, 0, stream>>>(Wh1, WT_h1, 576, HID_);
    split_transpose<<<dim3(3, HID_), 256, 0, stream>>>(Wt1, Wt1h, Wt1l, 576, HID_);
    split_transpose<<<dim3(4, HID_), 256, 0, stream>>>(Wt2, Wt2h, Wt2l, HID_, HID_);
    split_transpose<<<dim3(4, L_), 256, 0, stream>>>(Wt3, Wt3h, Wt3l, HID_, L_);

    init_split<<<(B_ * L_) / 256, 256, 0, stream>>>(initial, states, sth, stl);
    if (batched_ae)
        ae_all<<<(B_ * HOR_) / 4, 256, 0, stream>>>(actions, Wae, bae, ae);

    const int ldS = 33 * L_;
    const int lda_ae = batched_ae ? (HOR_ * A_) : A_;

    // ---- Phase 1: serial transition rollout (split-fp16 MFMA) ----
    for (int t = 0; t < HOR_; ++t) {
        if (!batched_ae)
            ae_step<<<B_ / 4, 256, 0, stream>>>(actions, Wae, bae, t, ae);
        const int aoff = batched_ae ? t * A_ : 0;
        // G1: h1 = relu([state, ae] @ Wt1^T + bt1)   128x128 tile, grid 256
        trans_gemm<128, 128, true, true, true, false, false>
            <<<dim3(HID_ / 128, B_ / 128), 512, 0, stream>>>(
            sth, stl, L_, 576, ae, lda_ae, aoff,
            Wt1h, Wt1l, bt1, nullptr, 0, h1h, h1l, HID_, nullptr, 0);
        // G2: h2 = relu(h1 @ Wt2^T + bt2)            128x128 tile, grid 256
        trans_gemm<128, 128, false, true, true, false, false>
            <<<dim3(HID_ / 128, B_ / 128), 512, 0, stream>>>(
            h1h, h1l, HID_, HID_, nullptr, 0, 0,
            Wt2h, Wt2l, bt2, nullptr, 0, h2h, h2l, HID_, nullptr, 0);
        // G3: next = state + h2 @ Wt3^T + bt3        64x64 tile, grid 512
        trans_gemm<64, 64, false, true, false, true, true>
            <<<dim3(L_ / 64, B_ / 64), 512, 0, stream>>>(
            h2h, h2l, HID_, HID_, nullptr, 0, 0,
            Wt3h, Wt3l, bt3, states + (size_t)t * L_, ldS,
            sth, stl, L_, states + (size_t)(t + 1) * L_, ldS);
    }

    // ---- Phase 2: batched obs + harm, 8 chunks of 512 batch ----
    for (int c = 0; c < B_ / CB; ++c) {
        const float* Sc = states + (size_t)c * CB * 33 * L_;
        const float* Ac = actions + (size_t)c * CB * HOR_ * A_;
        if (batched_ae) {
            split_chunk<<<(MC * 144) / 256, 256, 0, stream>>>(
                Sc, Ac, Ach_hi, Ach_lo);
            mm2<true, true, true><<<dim3(HID_ / 128, MC / 128), 512, 0, stream>>>(
                Ach_hi, Ach_lo, 576, L_, WT_o1, bo1, oh2, nullptr, HID_);
            mm2<false, false, false><<<dim3(L_ / 128, MC / 128), 512, 0, stream>>>(
                oh2, nullptr, HID_, HID_, WT_o2, bo2, nullptr,
                obs + (size_t)c * CB * HOR_ * L_, L_);
            mm2<true, true, true><<<dim3(HID_ / 128, MC / 128), 512, 0, stream>>>(
                Ach_hi, Ach_lo, 576, 576, WT_h1, bh1, oh2, nullptr, HID_);
            harm_reduce<<<MC / 4, 256, 0, stream>>>(
                oh2, Wh2, bh2, harm + (size_t)c * CB * HOR_);
        } else {
            mm_split<<<dim3(HID_ / 128, MC / 128), 256, 0, stream>>>(
                Sc, nullptr, L_, WT_o1, HID_, bo1, oh_fb);
            mm_bf16<<<dim3(L_ / 128, MC / 128), 256, 0, stream>>>(
                oh_fb, WT_o2, L_, bo2, obs + (size_t)c * CB * HOR_ * L_);
            mm_split<<<dim3(HID_ / 128, MC / 128), 256, 0, stream>>>(
                Sc, Ac, 576, WT_h1, HID_, bh1, oh_fb);
            harm_reduce<<<MC / 4, 256, 0, stream>>>(
                oh_fb, Wh2, bh2, harm + (size_t)c * CB * HOR_);
        }
    }
}

// Round 13
// 3696.087 us; speedup vs baseline: 1.0208x; 1.0208x over previous
//
#include <hip/hip_runtime.h>
#include <math.h>

// Problem dims
#define B_ 4096
#define HOR_ 32
#define L_ 512
#define A_ 64
#define HID_ 1024

// phase-2 chunking
#define CB 512            // batch rows per chunk
#define MC (CB * HOR_)    // 16384 rows per chunk

typedef unsigned short ushort_t;
typedef __attribute__((ext_vector_type(4))) float f32x4;
typedef __attribute__((ext_vector_type(8))) short s16x8;
typedef __attribute__((ext_vector_type(4))) short s16x4;
typedef __attribute__((ext_vector_type(8))) _Float16 f16x8;

__device__ __forceinline__ unsigned short bf16_rne(float x) {
    unsigned u = __builtin_bit_cast(unsigned, x);
    u += 0x7fffu + ((u >> 16) & 1u);
    return (unsigned short)(u >> 16);
}
__device__ __forceinline__ float bf16_to_f32(unsigned short h) {
    unsigned u = ((unsigned)h) << 16;
    return __builtin_bit_cast(float, u);
}

// XCD-chunked bijective swizzle (requires nwg % 8 == 0; all our grids are).
__device__ __forceinline__ int xcd_swz(int bid, int nwg) {
    return (bid & 7) * (nwg >> 3) + (bid >> 3);
}

// async global->LDS, 16 B per lane; LDS dst = wave-uniform base + lane*16.
__device__ __forceinline__ void gld16(const void* g, void* l) {
    __builtin_amdgcn_global_load_lds(
        (const __attribute__((address_space(1))) void*)g,
        (__attribute__((address_space(3))) void*)l, 16, 0, 0);
}

// ---------------------------------------------------------------------------
// Phase 1: split-fp16 MFMA transition GEMMs (round-11 best config).
//   C = act(A @ W^T + bias [+ resid]);  A = Ahi+Alo fp16 pair ([M][K]),
//   W = Whi+Wlo fp16 pair ([N][K]).  3-pass: Ah*Bh + Ah*Bl + Al*Bh, f32 accum.
// Tile BMT x NB, 512 threads, 8 waves as 4(M) x 2(N), wave tile
// (BMT/4) x (NB/2). gload_lds staging into linear [rows][32] LDS,
// double-buffered, 1 barrier/K-step, T1 swizzle. G1/G2: 128x64 (grid 512,
// 2 blk/CU); G3: 64x64 (grid 512, 2 blk/CU).
// ---------------------------------------------------------------------------
template <int BMT, int NB, bool TWOSRC, bool SPLIT_OUT, bool RELU, bool RESID,
          bool F32OUT>
__global__ __launch_bounds__(512, (NB == 128 ? 2 : 4)) void trans_gemm(
    const _Float16* __restrict__ Ahi, const _Float16* __restrict__ Alo,
    int lda, int K,
    const float* __restrict__ Aae, int lda_ae, int aoff,
    const _Float16* __restrict__ Whi, const _Float16* __restrict__ Wlo,
    const float* __restrict__ bias,
    const float* __restrict__ resid, int ldr,
    _Float16* __restrict__ Ohi, _Float16* __restrict__ Olo, int ldoh,
    float* __restrict__ Of, int ldof)
{
    constexpr int AF = BMT / 64;                 // M-frags per wave
    constexpr int BF = NB / 32;                  // N-frags per wave

    __shared__ _Float16 Ah[2][BMT][32];
    __shared__ _Float16 Al[2][BMT][32];
    __shared__ _Float16 Bh[2][NB][32];
    __shared__ _Float16 Bl[2][NB][32];

    const int gx = gridDim.x;
    const int bid = xcd_swz(blockIdx.y * gx + blockIdx.x, gx * gridDim.y);
    const int m0 = (bid / gx) * BMT;
    const int n0 = (bid % gx) * NB;

    const int tid = threadIdx.x;
    const int w = tid >> 6, l = tid & 63;
    const int wr = w >> 1, wc = w & 1;           // 4(M) x 2(N) waves
    const int kg = l >> 4, lr = l & 15;

    // staging role assignment: A needs BMT*4 threads, B needs NB*4.
    constexpr int ATH = BMT * 4;
    constexpr int BTH = NB * 4;
    const bool doA = (ATH == 512) || (tid < ATH);
    const bool doB = (ATH == 512) ? ((BTH == 512) || (tid < BTH))
                                  : (tid >= 512 - BTH);
    const int srowA = tid >> 2;
    const int srowB = (ATH == 512) ? (tid >> 2) : ((tid - (512 - BTH)) >> 2);
    const int sg = tid & 3;

    f32x4 acc[AF][BF] = {};
    float4 e0, e1;

    const _Float16* pAh = Ahi + (size_t)(m0 + srowA) * lda + sg * 8;
    const _Float16* pAl = Alo + (size_t)(m0 + srowA) * lda + sg * 8;
    const _Float16* pBh = Whi + (size_t)(n0 + srowB) * K + sg * 8;
    const _Float16* pBl = Wlo + (size_t)(n0 + srowB) * K + sg * 8;
    const float* pAe = TWOSRC
        ? (Aae + (size_t)(m0 + srowA) * lda_ae + aoff + sg * 8 - L_)
        : nullptr;

    auto stage = [&](int buf, int ks) {
        const int k0 = ks * 32;
        if (doB) {
            gld16(pBh + k0, &Bh[buf][srowB][sg * 8]);
            gld16(pBl + k0, &Bl[buf][srowB][sg * 8]);
        }
        if (doA && (!TWOSRC || k0 < L_)) {
            gld16(pAh + k0, &Ah[buf][srowA][sg * 8]);
            gld16(pAl + k0, &Al[buf][srowA][sg * 8]);
        }
    };

    const int NT = K / 32;
    stage(0, 0);
    __syncthreads();
    int cur = 0;

    for (int ks = 0; ks < NT; ++ks) {
        const bool havepf = (ks + 1 < NT);
        const int k0n = (ks + 1) * 32;
        const bool aeNext = TWOSRC && havepf && (k0n >= L_);

        if (havepf) {
            stage(cur ^ 1, ks + 1);
            if (aeNext && doA) {
                e0 = *reinterpret_cast<const float4*>(pAe + k0n);
                e1 = *reinterpret_cast<const float4*>(pAe + k0n + 4);
            }
        }

        f16x8 ah[AF], al[AF], bh[BF], bl[BF];
#pragma unroll
        for (int i = 0; i < AF; ++i) {
            int r = wr * (BMT / 4) + i * 16 + lr;
            ah[i] = *reinterpret_cast<const f16x8*>(&Ah[cur][r][kg * 8]);
            al[i] = *reinterpret_cast<const f16x8*>(&Al[cur][r][kg * 8]);
        }
#pragma unroll
        for (int j = 0; j < BF; ++j) {
            int r = wc * (NB / 2) + j * 16 + lr;
            bh[j] = *reinterpret_cast<const f16x8*>(&Bh[cur][r][kg * 8]);
            bl[j] = *reinterpret_cast<const f16x8*>(&Bl[cur][r][kg * 8]);
        }
#pragma unroll
        for (int i = 0; i < AF; ++i)
#pragma unroll
            for (int j = 0; j < BF; ++j) {
                acc[i][j] = __builtin_amdgcn_mfma_f32_16x16x32_f16(
                    ah[i], bh[j], acc[i][j], 0, 0, 0);
                acc[i][j] = __builtin_amdgcn_mfma_f32_16x16x32_f16(
                    ah[i], bl[j], acc[i][j], 0, 0, 0);
                acc[i][j] = __builtin_amdgcn_mfma_f32_16x16x32_f16(
                    al[i], bh[j], acc[i][j], 0, 0, 0);
            }

        if (havepf) {
            if (aeNext && doA) {
                float vv[8] = {e0.x, e0.y, e0.z, e0.w, e1.x, e1.y, e1.z, e1.w};
                f16x8 h, lo;
#pragma unroll
                for (int j = 0; j < 8; ++j) {
                    _Float16 hh = (_Float16)vv[j];
                    h[j] = hh;
                    lo[j] = (_Float16)(vv[j] - (float)hh);
                }
                *reinterpret_cast<f16x8*>(&Ah[cur ^ 1][srowA][sg * 8]) = h;
                *reinterpret_cast<f16x8*>(&Al[cur ^ 1][srowA][sg * 8]) = lo;
            }
            __syncthreads();
            cur ^= 1;
        }
    }

    float bv[BF];
#pragma unroll
    for (int j = 0; j < BF; ++j)
        bv[j] = bias[n0 + wc * (NB / 2) + j * 16 + lr];

#pragma unroll
    for (int i = 0; i < AF; ++i)
#pragma unroll
        for (int j = 0; j < BF; ++j)
#pragma unroll
            for (int r = 0; r < 4; ++r) {
                int row = m0 + wr * (BMT / 4) + i * 16 + kg * 4 + r;
                int col = n0 + wc * (NB / 2) + j * 16 + lr;
                float v = acc[i][j][r] + bv[j];
                if (RESID)
                    v += resid[(size_t)row * ldr + col];
                if (RELU) v = fmaxf(v, 0.f);
                if (F32OUT)
                    Of[(size_t)row * ldof + col] = v;
                if (SPLIT_OUT) {
                    _Float16 h = (_Float16)v;
                    Ohi[(size_t)row * ldoh + col] = h;
                    Olo[(size_t)row * ldoh + col] = (_Float16)(v - (float)h);
                }
            }
}

// W [K][N] f32 -> Whi/Wlo [N][K] fp16 split (once per call)
__global__ __launch_bounds__(256) void split_transpose(
    const float* __restrict__ W, _Float16* __restrict__ Whi,
    _Float16* __restrict__ Wlo, int K, int N)
{
    int k = blockIdx.x * 256 + threadIdx.x;
    int n = blockIdx.y;
    if (k < K) {
        float v = W[(size_t)k * N + n];
        _Float16 h = (_Float16)v;
        Whi[(size_t)n * K + k] = h;
        Wlo[(size_t)n * K + k] = (_Float16)(v - (float)h);
    }
}

// ae[b,t,:] = action[b,t] @ Wae + bae  for ALL (b,t); one wave per row.
__global__ __launch_bounds__(256) void ae_all(
    const float* __restrict__ actions, const float* __restrict__ Wae,
    const float* __restrict__ bae, float* __restrict__ ae)
{
    const long r = (long)blockIdx.x * 4 + (threadIdx.x >> 6);
    const int c = threadIdx.x & 63;
    const float* arow = actions + r * 64;
    float acc = bae[c];
#pragma unroll 16
    for (int k = 0; k < 64; ++k) acc = fmaf(arow[k], Wae[k * 64 + c], acc);
    ae[r * 64 + c] = acc;
}

// fallback: ae for one step t -> aeS [B][64]
__global__ __launch_bounds__(256) void ae_step(
    const float* __restrict__ actions, const float* __restrict__ Wae,
    const float* __restrict__ bae, int t, float* __restrict__ aeS)
{
    const long b = (long)blockIdx.x * 4 + (threadIdx.x >> 6);
    const int c = threadIdx.x & 63;
    const float* arow = actions + (b * HOR_ + t) * 64;
    float acc = bae[c];
#pragma unroll 16
    for (int k = 0; k < 64; ++k) acc = fmaf(arow[k], Wae[k * 64 + c], acc);
    aeS[b * 64 + c] = acc;
}

// states[:,0,:] = initial; sth/stl = split(initial)
__global__ __launch_bounds__(256) void init_split(
    const float* __restrict__ init, float* __restrict__ states,
    _Float16* __restrict__ sth, _Float16* __restrict__ stl)
{
    size_t i = (size_t)blockIdx.x * 256 + threadIdx.x;
    size_t b = i >> 9, l = i & 511;
    float v = init[i];
    states[b * (33 * L_) + l] = v;
    _Float16 h = (_Float16)v;
    sth[i] = h;
    stl[i] = (_Float16)(v - (float)h);
}

// ---------------- Phase 2: batched bf16 MFMA (obs + harm paths) -------------

// WT[n][k] = bf16(W[k][n])
__global__ __launch_bounds__(256) void cast_transpose(
    const float* __restrict__ W, ushort_t* __restrict__ WT, int K, int N)
{
    int k = blockIdx.x * 256 + threadIdx.x;
    int n = blockIdx.y;
    if (k < K) WT[(long)n * K + k] = bf16_rne(W[(long)k * N + n]);
}

// Per-chunk A-operand split: Ach_hi/lo[m][576] = split_bf16([state_t, act_t])
__global__ __launch_bounds__(256) void split_chunk(
    const float* __restrict__ Sc, const float* __restrict__ Ac,
    ushort_t* __restrict__ Hi, ushort_t* __restrict__ Lo)
{
    size_t i = (size_t)blockIdx.x * 256 + threadIdx.x;   // over MC*144
    int m = (int)(i / 144);
    int g = (int)(i % 144);
    const float* src = (g < 128)
        ? Sc + ((size_t)(m >> 5) * 33 + (m & 31)) * L_ + g * 4
        : Ac + (size_t)m * A_ + (g - 128) * 4;
    float4 v = *reinterpret_cast<const float4*>(src);
    unsigned short h0 = bf16_rne(v.x), h1 = bf16_rne(v.y),
                   h2 = bf16_rne(v.z), h3 = bf16_rne(v.w);
    unsigned short e0 = bf16_rne(v.x - bf16_to_f32(h0));
    unsigned short e1 = bf16_rne(v.y - bf16_to_f32(h1));
    unsigned short e2 = bf16_rne(v.z - bf16_to_f32(h2));
    unsigned short e3 = bf16_rne(v.w - bf16_to_f32(h3));
    s16x4 hv = {(short)h0, (short)h1, (short)h2, (short)h3};
    s16x4 lv = {(short)e0, (short)e1, (short)e2, (short)e3};
    *reinterpret_cast<s16x4*>(&Hi[(size_t)m * 576 + g * 4]) = hv;
    *reinterpret_cast<s16x4*>(&Lo[(size_t)m * 576 + g * 4]) = lv;
}

// Unified phase-2 bf16 GEMM: C = act(A @ WT^T + bias).
template <bool SPLITA, bool RELU, bool BF16OUT>
__global__ __launch_bounds__(512, 4) void mm2(
    const ushort_t* __restrict__ Ahi_g, const ushort_t* __restrict__ Alo_g,
    int lda, int K,
    const ushort_t* __restrict__ WT,
    const float* __restrict__ bias,
    ushort_t* __restrict__ Ob, float* __restrict__ Of, int N)
{
    __shared__ ushort_t Ah[2][128][32];
    __shared__ ushort_t Al[SPLITA ? 2 : 1][128][32];
    __shared__ ushort_t Bt[2][128][32];

    const int gx = gridDim.x;
    const int bid = xcd_swz(blockIdx.y * gx + blockIdx.x, gx * gridDim.y);
    const int m0 = (bid / gx) * 128;
    const int n0 = (bid % gx) * 128;

    const int tid = threadIdx.x;
    const int w = tid >> 6, l = tid & 63;
    const int wr = w >> 1, wc = w & 1;          // 4(M) x 2(N)
    const int kg = l >> 4, lr = l & 15;

    const int srow = tid >> 2, sg = tid & 3;

    f32x4 acc[2][4] = {};

    const ushort_t* pA0 = Ahi_g + (size_t)(m0 + srow) * lda + sg * 8;
    const ushort_t* pA1 = SPLITA
        ? (Alo_g + (size_t)(m0 + srow) * lda + sg * 8) : nullptr;
    const ushort_t* pB = WT + (size_t)(n0 + srow) * K + sg * 8;

    auto stage = [&](int buf, int ks) {
        const int k0 = ks * 32;
        gld16(pB + k0, &Bt[buf][srow][sg * 8]);
        gld16(pA0 + k0, &Ah[buf][srow][sg * 8]);
        if (SPLITA) gld16(pA1 + k0, &Al[SPLITA ? buf : 0][srow][sg * 8]);
    };

    const int NT = K / 32;
    stage(0, 0);
    __syncthreads();
    int cur = 0;

    for (int ks = 0; ks < NT; ++ks) {
        if (ks + 1 < NT) stage(cur ^ 1, ks + 1);

        s16x8 ah[2], al[2], bb[4];
#pragma unroll
        for (int i = 0; i < 2; ++i) {
            int r = wr * 32 + i * 16 + lr;
            ah[i] = *reinterpret_cast<const s16x8*>(&Ah[cur][r][kg * 8]);
            if (SPLITA)
                al[i] = *reinterpret_cast<const s16x8*>(
                    &Al[SPLITA ? cur : 0][r][kg * 8]);
        }
#pragma unroll
        for (int j = 0; j < 4; ++j) {
            int r = wc * 64 + j * 16 + lr;
            bb[j] = *reinterpret_cast<const s16x8*>(&Bt[cur][r][kg * 8]);
        }
#pragma unroll
        for (int i = 0; i < 2; ++i)
#pragma unroll
            for (int j = 0; j < 4; ++j) {
                acc[i][j] = __builtin_amdgcn_mfma_f32_16x16x32_bf16(
                    ah[i], bb[j], acc[i][j], 0, 0, 0);
                if (SPLITA)
                    acc[i][j] = __builtin_amdgcn_mfma_f32_16x16x32_bf16(
                        al[i], bb[j], acc[i][j], 0, 0, 0);
            }

        if (ks + 1 < NT) {
            __syncthreads();
            cur ^= 1;
        }
    }

    float bv[4];
#pragma unroll
    for (int j = 0; j < 4; ++j) bv[j] = bias[n0 + wc * 64 + j * 16 + lr];

#pragma unroll
    for (int i = 0; i < 2; ++i)
#pragma unroll
        for (int j = 0; j < 4; ++j)
#pragma unroll
            for (int r = 0; r < 4; ++r) {
                int row = m0 + wr * 32 + i * 16 + kg * 4 + r;
                int col = n0 + wc * 64 + j * 16 + lr;
                float v = acc[i][j][r] + bv[j];
                if (RELU) v = fmaxf(v, 0.f);
                if (BF16OUT)
                    Ob[(size_t)row * N + col] = bf16_rne(v);
                else
                    Of[(size_t)row * N + col] = v;
            }
}

// ----- fallback phase-2 kernels (reg-staged; used only if ws too small) -----
__global__ __launch_bounds__(256) void mm_split(
    const float* __restrict__ Astate, const float* __restrict__ Aact,
    int Ktot, const ushort_t* __restrict__ WT, int N,
    const float* __restrict__ bias, ushort_t* __restrict__ Out)
{
    __shared__ ushort_t Ahi[128][40];
    __shared__ ushort_t Alo[128][40];
    __shared__ ushort_t Bt[128][40];

    const int tid = threadIdx.x;
    const int m0 = blockIdx.y * 128;
    const int n0 = blockIdx.x * 128;
    const int w = tid >> 6;
    const int l = tid & 63;
    const int wm = w >> 1, wn = w & 1;
    const int kg = l >> 4, lr = l & 15;

    f32x4 acc[4][4] = {};

    for (int k0 = 0; k0 < Ktot; k0 += 32) {
#pragma unroll
        for (int s = 0; s < 4; ++s) {
            int idx = tid + s * 256;
            int arow = idx >> 3;
            int ch = idx & 7;
            int m = m0 + arow;
            const float* src;
            if (k0 < L_) {
                src = Astate + (long)((m >> 5) * 33 + (m & 31)) * L_ + k0 + ch * 4;
            } else {
                src = Aact + (long)m * A_ + (k0 - L_) + ch * 4;
            }
            float4 v = *reinterpret_cast<const float4*>(src);
            unsigned short h0 = bf16_rne(v.x), h1 = bf16_rne(v.y),
                           h2 = bf16_rne(v.z), h3 = bf16_rne(v.w);
            unsigned short e0 = bf16_rne(v.x - bf16_to_f32(h0));
            unsigned short e1 = bf16_rne(v.y - bf16_to_f32(h1));
            unsigned short e2 = bf16_rne(v.z - bf16_to_f32(h2));
            unsigned short e3 = bf16_rne(v.w - bf16_to_f32(h3));
            s16x4 hv = {(short)h0, (short)h1, (short)h2, (short)h3};
            s16x4 lv = {(short)e0, (short)e1, (short)e2, (short)e3};
            *reinterpret_cast<s16x4*>(&Ahi[arow][ch * 4]) = hv;
            *reinterpret_cast<s16x4*>(&Alo[arow][ch * 4]) = lv;
        }
#pragma unroll
        for (int s = 0; s < 2; ++s) {
            int idx = tid + s * 256;
            int brow = idx >> 2;
            int ch = idx & 3;
            s16x8 wv = *reinterpret_cast<const s16x8*>(
                &WT[(long)(n0 + brow) * Ktot + k0 + ch * 8]);
            *reinterpret_cast<s16x8*>(&Bt[brow][ch * 8]) = wv;
        }
        __syncthreads();

        s16x8 ah[4], al[4], bb[4];
#pragma unroll
        for (int i = 0; i < 4; ++i) {
            int r = wm * 64 + i * 16 + lr;
            ah[i] = *reinterpret_cast<const s16x8*>(&Ahi[r][kg * 8]);
            al[i] = *reinterpret_cast<const s16x8*>(&Alo[r][kg * 8]);
        }
#pragma unroll
        for (int j = 0; j < 4; ++j) {
            int r = wn * 64 + j * 16 + lr;
            bb[j] = *reinterpret_cast<const s16x8*>(&Bt[r][kg * 8]);
        }
#pragma unroll
        for (int i = 0; i < 4; ++i)
#pragma unroll
            for (int j = 0; j < 4; ++j) {
                acc[i][j] = __builtin_amdgcn_mfma_f32_16x16x32_bf16(
                    ah[i], bb[j], acc[i][j], 0, 0, 0);
                acc[i][j] = __builtin_amdgcn_mfma_f32_16x16x32_bf16(
                    al[i], bb[j], acc[i][j], 0, 0, 0);
            }
        __syncthreads();
    }

    float bv[4];
#pragma unroll
    for (int j = 0; j < 4; ++j) bv[j] = bias[n0 + wn * 64 + j * 16 + lr];
#pragma unroll
    for (int i = 0; i < 4; ++i)
#pragma unroll
        for (int j = 0; j < 4; ++j)
#pragma unroll
            for (int r = 0; r < 4; ++r) {
                int row = m0 + wm * 64 + i * 16 + kg * 4 + r;
                int col = n0 + wn * 64 + j * 16 + lr;
                float v = fmaxf(acc[i][j][r] + bv[j], 0.f);
                Out[(long)row * N + col] = bf16_rne(v);
            }
}

__global__ __launch_bounds__(256) void mm_bf16(
    const ushort_t* __restrict__ Abf, const ushort_t* __restrict__ WT,
    int N, const float* __restrict__ bias, float* __restrict__ Out)
{
    __shared__ ushort_t At[128][40];
    __shared__ ushort_t Bt[128][40];

    const int tid = threadIdx.x;
    const int m0 = blockIdx.y * 128;
    const int n0 = blockIdx.x * 128;
    const int w = tid >> 6;
    const int l = tid & 63;
    const int wm = w >> 1, wn = w & 1;
    const int kg = l >> 4, lr = l & 15;

    f32x4 acc[4][4] = {};

    for (int k0 = 0; k0 < HID_; k0 += 32) {
#pragma unroll
        for (int s = 0; s < 2; ++s) {
            int idx = tid + s * 256;
            int arow = idx >> 2;
            int ch = idx & 3;
            s16x8 av = *reinterpret_cast<const s16x8*>(
                &Abf[(long)(m0 + arow) * HID_ + k0 + ch * 8]);
            *reinterpret_cast<s16x8*>(&At[arow][ch * 8]) = av;
        }
#pragma unroll
        for (int s = 0; s < 2; ++s) {
            int idx = tid + s * 256;
            int brow = idx >> 2;
            int ch = idx & 3;
            s16x8 wv = *reinterpret_cast<const s16x8*>(
                &WT[(long)(n0 + brow) * HID_ + k0 + ch * 8]);
            *reinterpret_cast<s16x8*>(&Bt[brow][ch * 8]) = wv;
        }
        __syncthreads();

        s16x8 aa[4], bb[4];
#pragma unroll
        for (int i = 0; i < 4; ++i)
            aa[i] = *reinterpret_cast<const s16x8*>(&At[wm * 64 + i * 16 + lr][kg * 8]);
#pragma unroll
        for (int j = 0; j < 4; ++j)
            bb[j] = *reinterpret_cast<const s16x8*>(&Bt[wn * 64 + j * 16 + lr][kg * 8]);
#pragma unroll
        for (int i = 0; i < 4; ++i)
#pragma unroll
            for (int j = 0; j < 4; ++j)
                acc[i][j] = __builtin_amdgcn_mfma_f32_16x16x32_bf16(
                    aa[i], bb[j], acc[i][j], 0, 0, 0);
        __syncthreads();
    }

    float bv[4];
#pragma unroll
    for (int j = 0; j < 4; ++j) bv[j] = bias[n0 + wn * 64 + j * 16 + lr];
#pragma unroll
    for (int i = 0; i < 4; ++i)
#pragma unroll
        for (int j = 0; j < 4; ++j)
#pragma unroll
            for (int r = 0; r < 4; ++r) {
                int row = m0 + wm * 64 + i * 16 + kg * 4 + r;
                int col = n0 + wn * 64 + j * 16 + lr;
                Out[(long)row * N + col] = acc[i][j][r] + bv[j];
            }
}

// harm[m] = sigmoid(hh[m][:] . Wh2 + bh2), one wave per row.
__global__ __launch_bounds__(256) void harm_reduce(
    const ushort_t* __restrict__ hh, const float* __restrict__ Wh2,
    const float* __restrict__ bh2, float* __restrict__ harm)
{
    const int wave = threadIdx.x >> 6;
    const int lane = threadIdx.x & 63;
    const long r = (long)blockIdx.x * 4 + wave;
    const ushort_t* row = hh + r * HID_;
    float s = 0.f;
#pragma unroll
    for (int q = 0; q < 2; ++q) {
        s16x8 a = *reinterpret_cast<const s16x8*>(&row[lane * 16 + q * 8]);
        float4 w0 = *reinterpret_cast<const float4*>(&Wh2[lane * 16 + q * 8]);
        float4 w1 = *reinterpret_cast<const float4*>(&Wh2[lane * 16 + q * 8 + 4]);
        s = fmaf(bf16_to_f32((unsigned short)a[0]), w0.x, s);
        s = fmaf(bf16_to_f32((unsigned short)a[1]), w0.y, s);
        s = fmaf(bf16_to_f32((unsigned short)a[2]), w0.z, s);
        s = fmaf(bf16_to_f32((unsigned short)a[3]), w0.w, s);
        s = fmaf(bf16_to_f32((unsigned short)a[4]), w1.x, s);
        s = fmaf(bf16_to_f32((unsigned short)a[5]), w1.y, s);
        s = fmaf(bf16_to_f32((unsigned short)a[6]), w1.z, s);
        s = fmaf(bf16_to_f32((unsigned short)a[7]), w1.w, s);
    }
#pragma unroll
    for (int off = 32; off; off >>= 1) s += __shfl_down(s, off);
    if (lane == 0) {
        float x = s + bh2[0];
        harm[r] = 1.f / (1.f + expf(-x));
    }
}

// ---------------------------------------------------------------------------
extern "C" void kernel_launch(void* const* d_in, const int* in_sizes, int n_in,
                              void* d_out, int out_size, void* d_ws, size_t ws_size,
                              hipStream_t stream)
{
    const float* initial = (const float*)d_in[0];
    const float* actions = (const float*)d_in[1];
    const float* Wae = (const float*)d_in[2];
    const float* bae = (const float*)d_in[3];
    const float* Wt1 = (const float*)d_in[4];
    const float* bt1 = (const float*)d_in[5];
    const float* Wt2 = (const float*)d_in[6];
    const float* bt2 = (const float*)d_in[7];
    const float* Wt3 = (const float*)d_in[8];
    const float* bt3 = (const float*)d_in[9];
    const float* Wo1 = (const float*)d_in[10];
    const float* bo1 = (const float*)d_in[11];
    const float* Wo2 = (const float*)d_in[12];
    const float* bo2 = (const float*)d_in[13];
    const float* Wh1 = (const float*)d_in[14];
    const float* bh1 = (const float*)d_in[15];
    const float* Wh2 = (const float*)d_in[16];
    const float* bh2 = (const float*)d_in[17];

    float* out = (float*)d_out;
    float* states = out;                                    // [B][33][512]
    float* obs = out + (size_t)B_ * 33 * L_;                // [B][32][512]
    float* harm = obs + (size_t)B_ * HOR_ * L_;             // [B][32]

    // ws layout
    char* wsb = (char*)d_ws;
    size_t off = 0;
    auto alloc = [&](size_t bytes) { char* q = wsb + off; off += bytes; return q; };
    ushort_t* WT_o1 = (ushort_t*)alloc((size_t)HID_ * L_ * 2);
    ushort_t* WT_o2 = (ushort_t*)alloc((size_t)L_ * HID_ * 2);
    ushort_t* WT_h1 = (ushort_t*)alloc((size_t)HID_ * 576 * 2);
    _Float16* Wt1h = (_Float16*)alloc((size_t)HID_ * 576 * 2);
    _Float16* Wt1l = (_Float16*)alloc((size_t)HID_ * 576 * 2);
    _Float16* Wt2h = (_Float16*)alloc((size_t)HID_ * HID_ * 2);
    _Float16* Wt2l = (_Float16*)alloc((size_t)HID_ * HID_ * 2);
    _Float16* Wt3h = (_Float16*)alloc((size_t)L_ * HID_ * 2);
    _Float16* Wt3l = (_Float16*)alloc((size_t)L_ * HID_ * 2);
    _Float16* sth  = (_Float16*)alloc((size_t)B_ * L_ * 2);
    _Float16* stl  = (_Float16*)alloc((size_t)B_ * L_ * 2);
    _Float16* h1h  = (_Float16*)alloc((size_t)B_ * HID_ * 2);
    _Float16* h1l  = (_Float16*)alloc((size_t)B_ * HID_ * 2);
    _Float16* h2h  = (_Float16*)alloc((size_t)B_ * HID_ * 2);
    _Float16* h2l  = (_Float16*)alloc((size_t)B_ * HID_ * 2);
    float* ae = (float*)alloc(0);  // placed last; size depends on mode
    const size_t need_batched = off + (size_t)B_ * HOR_ * A_ * 4;
    const bool batched_ae = (ws_size >= need_batched);

    // phase-2 buffers overlay phase-1 regions (dead after phase 1)
    ushort_t* Ach_hi = (ushort_t*)sth;
    ushort_t* Ach_lo = Ach_hi + (size_t)MC * 576;
    ushort_t* oh2 = (ushort_t*)ae;
    ushort_t* oh_fb = (ushort_t*)h1h;

    // one-time weight prep
    cast_transpose<<<dim3(2, HID_), 256, 0, stream>>>(Wo1, WT_o1, L_, HID_);
    cast_transpose<<<dim3(4, L_), 256, 0, stream>>>(Wo2, WT_o2, HID_, L_);
    cast_transpose<<<dim3(3, HID_), 256, 0, stream>>>(Wh1, WT_h1, 576, HID_);
    split_transpose<<<dim3(3, HID_), 256, 0, stream>>>(Wt1, Wt1h, Wt1l, 576, HID_);
    split_transpose<<<dim3(4, HID_), 256, 0, stream>>>(Wt2, Wt2h, Wt2l, HID_, HID_);
    split_transpose<<<dim3(4, L_), 256, 0, stream>>>(Wt3, Wt3h, Wt3l, HID_, L_);

    init_split<<<(B_ * L_) / 256, 256, 0, stream>>>(initial, states, sth, stl);
    if (batched_ae)
        ae_all<<<(B_ * HOR_) / 4, 256, 0, stream>>>(actions, Wae, bae, ae);

    const int ldS = 33 * L_;
    const int lda_ae = batched_ae ? (HOR_ * A_) : A_;

    // ---- Phase 1: serial transition rollout (split-fp16 MFMA) ----
    for (int t = 0; t < HOR_; ++t) {
        if (!batched_ae)
            ae_step<<<B_ / 4, 256, 0, stream>>>(actions, Wae, bae, t, ae);
        const int aoff = batched_ae ? t * A_ : 0;
        // G1: h1 = relu([state, ae] @ Wt1^T + bt1)   128x64 tile, grid 512
        trans_gemm<128, 64, true, true, true, false, false>
            <<<dim3(HID_ / 64, B_ / 128), 512, 0, stream>>>(
            sth, stl, L_, 576, ae, lda_ae, aoff,
            Wt1h, Wt1l, bt1, nullptr, 0, h1h, h1l, HID_, nullptr, 0);
        // G2: h2 = relu(h1 @ Wt2^T + bt2)            128x64 tile, grid 512
        trans_gemm<128, 64, false, true, true, false, false>
            <<<dim3(HID_ / 64, B_ / 128), 512, 0, stream>>>(
            h1h, h1l, HID_, HID_, nullptr, 0, 0,
            Wt2h, Wt2l, bt2, nullptr, 0, h2h, h2l, HID_, nullptr, 0);
        // G3: next = state + h2 @ Wt3^T + bt3        64x64 tile, grid 512
        trans_gemm<64, 64, false, true, false, true, true>
            <<<dim3(L_ / 64, B_ / 64), 512, 0, stream>>>(
            h2h, h2l, HID_, HID_, nullptr, 0, 0,
            Wt3h, Wt3l, bt3, states + (size_t)t * L_, ldS,
            sth, stl, L_, states + (size_t)(t + 1) * L_, ldS);
    }

    // ---- Phase 2: batched obs + harm, 8 chunks of 512 batch ----
    for (int c = 0; c < B_ / CB; ++c) {
        const float* Sc = states + (size_t)c * CB * 33 * L_;
        const float* Ac = actions + (size_t)c * CB * HOR_ * A_;
        if (batched_ae) {
            split_chunk<<<(MC * 144) / 256, 256, 0, stream>>>(
                Sc, Ac, Ach_hi, Ach_lo);
            mm2<true, true, true><<<dim3(HID_ / 128, MC / 128), 512, 0, stream>>>(
                Ach_hi, Ach_lo, 576, L_, WT_o1, bo1, oh2, nullptr, HID_);
            mm2<false, false, false><<<dim3(L_ / 128, MC / 128), 512, 0, stream>>>(
                oh2, nullptr, HID_, HID_, WT_o2, bo2, nullptr,
                obs + (size_t)c * CB * HOR_ * L_, L_);
            mm2<true, true, true><<<dim3(HID_ / 128, MC / 128), 512, 0, stream>>>(
                Ach_hi, Ach_lo, 576, 576, WT_h1, bh1, oh2, nullptr, HID_);
            harm_reduce<<<MC / 4, 256, 0, stream>>>(
                oh2, Wh2, bh2, harm + (size_t)c * CB * HOR_);
        } else {
            mm_split<<<dim3(HID_ / 128, MC / 128), 256, 0, stream>>>(
                Sc, nullptr, L_, WT_o1, HID_, bo1, oh_fb);
            mm_bf16<<<dim3(L_ / 128, MC / 128), 256, 0, stream>>>(
                oh_fb, WT_o2, L_, bo2, obs + (size_t)c * CB * HOR_ * L_);
            mm_split<<<dim3(HID_ / 128, MC / 128), 256, 0, stream>>>(
                Sc, Ac, 576, WT_h1, HID_, bh1, oh_fb);
            harm_reduce<<<MC / 4, 256, 0, stream>>>(
                oh_fb, Wh2, bh2, harm + (size_t)c * CB * HOR_);
        }
    }
}